// Round 3
// baseline (440.057 us; speedup 1.0000x reference)
//
#include <hip/hip_runtime.h>
#include <stdint.h>
#include <stddef.h>

#define OBS 128
#define F1D 256
#define HD  128
#define NA  18
#define TT  128
#define BB  1024
#define NN  (TT*BB)
#define LOG2E 1.442695041f

typedef __attribute__((ext_vector_type(8))) short short8;
typedef __attribute__((ext_vector_type(4))) float f32x4;

__device__ __forceinline__ unsigned short f2bf(float f) {
  union { float f; uint32_t u; } v; v.f = f;
  uint32_t u = v.u;
  u += 0x7fffu + ((u >> 16) & 1u);   // RNE
  return (unsigned short)(u >> 16);
}
__device__ __forceinline__ float bf2f(uint32_t hu) {
  union { uint32_t u; float f; } v; v.u = hu << 16;
  return v.f;
}
// packed bf16 convert — v_cvt_pk_bf16_f32 (RNE), 1 instr for 2 values.
__device__ __forceinline__ uint32_t pk2(float lo, float hi) {
  uint32_t r;
  asm("v_cvt_pk_bf16_f32 %0, %1, %2" : "=v"(r) : "v"(lo), "v"(hi));
  return r;
}
__device__ __forceinline__ f32x4 mfma16(short8 a, short8 b, f32x4 c) {
  return __builtin_amdgcn_mfma_f32_16x16x32_bf16(a, b, c, 0, 0, 0);
}
// f32 -> bf16 fragment (8 consecutive, scaled) via packed converts
__device__ __forceinline__ short8 cvt8(const float* p, float sc) {
  float4 a = *(const float4*)p;
  float4 b = *(const float4*)(p + 4);
  union { uint32_t u[4]; short8 s; } o;
  o.u[0] = pk2(a.x*sc, a.y*sc);
  o.u[1] = pk2(a.z*sc, a.w*sc);
  o.u[2] = pk2(b.x*sc, b.y*sc);
  o.u[3] = pk2(b.z*sc, b.w*sc);
  return o.s;
}
// pin: empty volatile asm with tied SCALAR "+v" operands (R6/R7 lessons).
__device__ __forceinline__ short8 pin(short8 v) {
  int4 i = *(int4*)&v;
  asm volatile("" : "+v"(i.x), "+v"(i.y), "+v"(i.z), "+v"(i.w));
  return *(short8*)&i;
}
// R12: LDS-only barrier — legal ONLY where no global stores need barrier
// ordering (LSTM loop is now store-free; prefetch loads are per-thread
// dataflow ordered by compiler vmcnt). Keeps prefetch in flight across
// the barrier instead of __syncthreads' vmcnt(0) drain.
__device__ __forceinline__ void bar_lds() {
  asm volatile("s_waitcnt lgkmcnt(0)" ::: "memory");
  __builtin_amdgcn_s_barrier();
  asm volatile("" ::: "memory");
}

// ================= Kernel A: feature MLP (both branches) =================
// Unchanged from R11 (full __syncthreads: loop has scattered global stores,
// the R10 failure mode — do NOT convert these to bar_lds).
__global__ __launch_bounds__(512, 2) void feat_kernel(
    const float* __restrict__ x,
    const float* __restrict__ aw1, const float* __restrict__ ab1,
    const float* __restrict__ aw2, const float* __restrict__ ab2,
    const float* __restrict__ aflnw, const float* __restrict__ aflnb,
    const float* __restrict__ cw1, const float* __restrict__ cb1,
    const float* __restrict__ cw2, const float* __restrict__ cb2,
    const float* __restrict__ cflnw, const float* __restrict__ cflnb,
    unsigned short* __restrict__ featg)
{
  int g = blockIdx.x;
  int br = g >> 7;
  int chunk = g & 127;
  int base8 = chunk * 8;

  const float* w1  = br ? cw1 : aw1;     // [256][128]
  const float* b1  = br ? cb1 : ab1;
  const float* w2  = br ? cw2 : aw2;     // [128][256]
  const float* b2  = br ? cb2 : ab2;
  const float* flw = br ? cflnw : aflnw;
  const float* flb = br ? cflnb : aflnb;
  unsigned short* feat = featg + (size_t)br * NN * HD;

  __shared__ __align__(16) char smemA[51200];  // xs(16K)+h1s(32K)+lnsum(2K)

  int tid = threadIdx.x;
  int w = tid >> 6, lane = tid & 63, q = lane >> 4, ln = lane & 15;
  int team = tid >> 8, t_tid = tid & 255, w4 = w & 3;

  unsigned short* xst  = (unsigned short*)smemA + team*4096;           // 32*128
  unsigned short* h1st = (unsigned short*)(smemA + 16384) + team*8192; // 32*256
  float*          lnst = (float*)(smemA + 49152) + team*256;           // 32*8

  short8 b1f[4][4]; float b1v[4];
  #pragma unroll
  for (int ct = 0; ct < 4; ++ct) {
    int nn = w4*64 + ct*16 + ln;
    b1v[ct] = b1[nn];
    #pragma unroll
    for (int kf = 0; kf < 4; ++kf)
      b1f[ct][kf] = pin(cvt8(&w1[nn*OBS + kf*32 + q*8], 1.0f));
  }
  short8 b2f[2][8]; float b2v[2], lwv[2], lbv[2];
  #pragma unroll
  for (int nt = 0; nt < 2; ++nt) {
    int nn = w4*32 + nt*16 + ln;
    b2v[nt] = b2[nn]; lwv[nt] = flw[nn]; lbv[nt] = flb[nn];
    #pragma unroll
    for (int kf = 0; kf < 8; ++kf)
      b2f[nt][kf] = pin(cvt8(&w2[nn*F1D + kf*32 + q*8], 1.0f));
  }
  // tile = 4 timesteps x 8 batch rows = 32 rows; team handles tiles 2j+team
  float4 xr[4];
  #pragma unroll
  for (int s = 0; s < 4; ++s) {
    int e4 = t_tid + s*256;
    int r = e4 >> 5, c4 = e4 & 31;
    size_t grow = (size_t)(team*4 + (r>>3))*BB + base8 + (r&7);
    xr[s] = ((const float4*)x)[grow*32 + c4];
  }
  for (int j = 0; j < 16; ++j) {
    int jj = j*2 + team;
    #pragma unroll
    for (int s = 0; s < 4; ++s) {
      int e = (t_tid + s*256) * 4;
      int r = e >> 7, k = e & 127;
      int ad = r*128 + ((((k>>3) ^ (r&15)) << 3)) + (k&7);
      uint2 d;
      d.x = pk2(xr[s].x, xr[s].y);
      d.y = pk2(xr[s].z, xr[s].w);
      *(uint2*)&xst[ad] = d;
    }
    __syncthreads();                 // B1: xs ready
    {
      int jjn = (j < 15) ? jj + 2 : jj;
      #pragma unroll
      for (int s = 0; s < 4; ++s) {
        int e4 = t_tid + s*256;
        int r = e4 >> 5, c4 = e4 & 31;
        size_t grow = (size_t)(jjn*4 + (r>>3))*BB + base8 + (r&7);
        xr[s] = ((const float4*)x)[grow*32 + c4];
      }
    }
    // ---- G1 ----
    short8 af[2][4];
    #pragma unroll
    for (int mt = 0; mt < 2; ++mt)
      #pragma unroll
      for (int kf = 0; kf < 4; ++kf)
        af[mt][kf] = *(const short8*)&xst[(mt*16 + ln)*128 + ((((kf<<2)|q) ^ ln) << 3)];
    #pragma unroll
    for (int ct = 0; ct < 4; ++ct) {
      int nn = w4*64 + ct*16 + ln;
      #pragma unroll
      for (int mt = 0; mt < 2; ++mt) {
        f32x4 acc = {b1v[ct], b1v[ct], b1v[ct], b1v[ct]};
        #pragma unroll
        for (int kf = 0; kf < 4; ++kf) acc = mfma16(af[mt][kf], b1f[ct][kf], acc);
        float v0 = acc[0] > 0.0f ? acc[0] : 0.0f;
        float v1 = acc[1] > 0.0f ? acc[1] : 0.0f;
        float v2 = acc[2] > 0.0f ? acc[2] : 0.0f;
        float v3 = acc[3] > 0.0f ? acc[3] : 0.0f;
        uint32_t p01 = pk2(v0, v1), p23 = pk2(v2, v3);
        int r0 = mt*16 + q*4;
        h1st[(r0+0)*256 + (((nn>>3) ^ ((r0+0)&15)) << 3) + (nn&7)] = (unsigned short)p01;
        h1st[(r0+1)*256 + (((nn>>3) ^ ((r0+1)&15)) << 3) + (nn&7)] = (unsigned short)(p01 >> 16);
        h1st[(r0+2)*256 + (((nn>>3) ^ ((r0+2)&15)) << 3) + (nn&7)] = (unsigned short)p23;
        h1st[(r0+3)*256 + (((nn>>3) ^ ((r0+3)&15)) << 3) + (nn&7)] = (unsigned short)(p23 >> 16);
      }
    }
    __syncthreads();                 // B2: h1s ready
    // ---- G2 ----
    f32x4 acc2[2][2];
    #pragma unroll
    for (int mt = 0; mt < 2; ++mt) {
      short8 ah[8];
      #pragma unroll
      for (int kf = 0; kf < 8; ++kf)
        ah[kf] = *(const short8*)&h1st[(mt*16 + ln)*256 + ((((kf<<2)|q) ^ ln) << 3)];
      #pragma unroll
      for (int nt = 0; nt < 2; ++nt) {
        f32x4 acc = {b2v[nt], b2v[nt], b2v[nt], b2v[nt]};
        #pragma unroll
        for (int kf = 0; kf < 8; ++kf) acc = mfma16(ah[kf], b2f[nt][kf], acc);
        acc2[nt][mt] = acc;
      }
    }
    // ---- LN partials ----
    #pragma unroll
    for (int mt = 0; mt < 2; ++mt)
      #pragma unroll
      for (int rg = 0; rg < 4; ++rg) {
        float s = acc2[0][mt][rg] + acc2[1][mt][rg];
        float ssq = acc2[0][mt][rg]*acc2[0][mt][rg] + acc2[1][mt][rg]*acc2[1][mt][rg];
        #pragma unroll
        for (int m = 1; m < 16; m <<= 1) { s += __shfl_xor(s, m); ssq += __shfl_xor(ssq, m); }
        if (ln == 0) {
          int r = mt*16 + q*4 + rg;
          lnst[r*8 + w4*2]     = s;
          lnst[r*8 + w4*2 + 1] = ssq;
        }
      }
    __syncthreads();                 // B3: lnsum ready
    #pragma unroll
    for (int mt = 0; mt < 2; ++mt)
      #pragma unroll
      for (int rg = 0; rg < 4; ++rg) {
        int r = mt*16 + q*4 + rg;
        float4 p0 = *(const float4*)&lnst[r*8];
        float4 p1 = *(const float4*)&lnst[r*8 + 4];
        float S  = p0.x + p0.z + p1.x + p1.z;
        float SS = p0.y + p0.w + p1.y + p1.w;
        float mu = S * (1.0f/128.0f);
        float var = SS * (1.0f/128.0f) - mu*mu;
        float rstd = rsqrtf(var + 1e-5f);
        size_t grow = (size_t)(jj*4 + (r>>3))*BB + base8 + (r&7);
        float t0 = (acc2[0][mt][rg] - mu) * rstd * lwv[0] + lbv[0];
        float t1 = (acc2[1][mt][rg] - mu) * rstd * lwv[1] + lbv[1];
        if (t0 < 0.0f) t0 = 0.0f;
        if (t1 < 0.0f) t1 = 0.0f;
        uint32_t p = pk2(t0, t1);
        unsigned short* fp = &feat[grow*HD + w4*32 + ln];
        fp[0]  = (unsigned short)p;
        fp[16] = (unsigned short)(p >> 16);
      }
    __syncthreads();                 // Bend
  }
}

// ================= Kernel BC: masked LSTM + heads =================
// R12: LSTM loop is now global-store-free. h history accumulates in a
// 16-slot LDS ring (unmasked) and is flushed to feat every 8 steps with
// coalesced dwordx4 stores. Per-step barrier is lgkm-only (bar_lds) so the
// feat[t+1] prefetch loads stay in flight across it — __syncthreads' vmcnt(0)
// drain was serializing every step on its own just-issued prefetch.
__global__ __launch_bounds__(512, 2) void lstm_head_kernel(
    const int* __restrict__ done, const int* __restrict__ action,
    const float* __restrict__ awih, const float* __restrict__ awhh,
    const float* __restrict__ a_b,
    const float* __restrict__ alnw, const float* __restrict__ alnb,
    const float* __restrict__ ahw, const float* __restrict__ ahb,
    const float* __restrict__ cwih, const float* __restrict__ cwhh,
    const float* __restrict__ c_b,
    const float* __restrict__ clnw, const float* __restrict__ clnb,
    const float* __restrict__ chw, const float* __restrict__ chb,
    const float* __restrict__ ah0, const float* __restrict__ ac0,
    const float* __restrict__ ch0, const float* __restrict__ cc0,
    unsigned short* __restrict__ featg, float* __restrict__ dout)
{
  int g = blockIdx.x;
  int br = g >> 7;
  int chunk = g & 127;
  int base8 = chunk * 8;

  const float* wih = br ? cwih : awih;   // [512][128]
  const float* whh = br ? cwhh : awhh;
  const float* gb  = br ? c_b : a_b;
  const float* h0  = br ? ch0 : ah0;
  const float* c0  = br ? cc0 : ac0;
  unsigned short* feat = featg + (size_t)br * NN * HD;

  __shared__ __align__(16) char smemC[51200];  // Phase C: hsn(32K)+cout(18K)
  __shared__ unsigned short ring[16*1024];     // h-history ring: 16 slots x [8][128] swizzled
  __shared__ float mls[(TT+1)*8];              // 1 - done, padded t=TT
  __shared__ unsigned short hlds[2][8*128];    // double-buffered masked h
  __shared__ float pa[HD], pb[HD], cws[HD];
  __shared__ float hbl[NA];
  __shared__ float cbsS;
  __shared__ int flagS;

  int tid = threadIdx.x;
  int w = tid >> 6, lane = tid & 63, q = lane >> 4, ln = lane & 15;

  // ================= Phase B: masked LSTM (M=8, stride-2 packing) =================
  int n = w*16 + ln;
  {
    short8 bfr[4][8]; float bias[4];
    #pragma unroll
    for (int g4 = 0; g4 < 4; ++g4) {
      int gn = g4*128 + n;
      float sc = (g4 == 2) ? -2.0f*LOG2E : -LOG2E;   // gate order i,f,g,o
      bias[g4] = gb[gn] * sc;
      #pragma unroll
      for (int kf = 0; kf < 8; ++kf) {
        const float* src = (kf < 4) ? &wih[gn*HD + kf*32 + q*8]
                                    : &whh[gn*HD + (kf-4)*32 + q*8];
        bfr[g4][kf] = pin(cvt8(src, sc));
      }
    }
    for (int i = tid; i < (TT+1)*8; i += 512)
      mls[i] = (i < TT*8) ? 1.0f - (float)done[(i>>3)*BB + base8 + (i&7)] : 1.0f;

    const int loff = (base8 + (ln>>1))*HD + q*8;   // A-row ln -> batch row ln>>1
    int hoffw[2], haddr[4];
    #pragma unroll
    for (int j = 0; j < 2; ++j) {
      int r = q*2 + j;
      hoffw[j] = r*128 + (((n>>3) ^ r) << 3) + (n&7);
    }
    #pragma unroll
    for (int kf = 0; kf < 4; ++kf) {
      int rr = ln >> 1;
      haddr[kf] = rr*128 + ((((kf<<2)|q) ^ rr) << 3);
    }
    float hp[2], cp[2];
    #pragma unroll
    for (int j = 0; j < 2; ++j) {
      int b = base8 + q*2 + j;
      hp[j] = h0[b*HD + n];
      cp[j] = c0[b*HD + n];
    }
    __syncthreads();   // mls ready (feat visible via kernel boundary)
    short8 afr[4], nfr[4];
    #pragma unroll
    for (int kf = 0; kf < 4; ++kf)
      afr[kf] = *(const short8*)&feat[loff + kf*32];    // feat[0]
    {
      float m0 = mls[q*2], m1 = mls[q*2 + 1];
      cp[0] *= m0; cp[1] *= m1;
      uint32_t hpk = pk2(hp[0]*m0, hp[1]*m1);
      hlds[0][hoffw[0]] = (unsigned short)hpk;
      hlds[0][hoffw[1]] = (unsigned short)(hpk >> 16);
    }
    __syncthreads();   // hlds[0] ready

// Flush 8 ring slots (t-planes TB..TB+7) to feat, coalesced.
// wave s handles plane TB+s: lane -> (row fr, 16-col block fc).
#define FLUSH(TB)                                                              \
  {                                                                            \
    int tp2 = (TB) + (tid >> 6);                                               \
    int ss = (tp2 & 15) << 10;                                                 \
    int fr = lane >> 3, fc = lane & 7;                                         \
    int b0 = ((fc*2) ^ fr) << 3, b1 = ((fc*2+1) ^ fr) << 3;                    \
    short8 v0 = *(const short8*)&ring[ss + fr*128 + b0];                       \
    short8 v1 = *(const short8*)&ring[ss + fr*128 + b1];                       \
    unsigned short* dst = feat + ((size_t)tp2*BB + base8 + fr)*HD + fc*16;     \
    *(short8*)dst = v0;                                                        \
    *(short8*)(dst + 8) = v1;                                                  \
  }

#define LSTM_STEP(TTT, CUR, NXT, HB)                                           \
  {                                                                            \
    short8 hfr[4];                                                             \
    _Pragma("unroll")                                                          \
    for (int kf = 0; kf < 4; ++kf)                                             \
      hfr[kf] = *(const short8*)&hlds[HB][haddr[kf]];                          \
    int tn = ((TTT) + 1 < TT) ? (TTT) + 1 : TT - 1;                            \
    const unsigned short* fq = feat + (size_t)tn * (BB*HD);                    \
    _Pragma("unroll")                                                          \
    for (int kf = 0; kf < 4; ++kf)                                             \
      NXT[kf] = *(const short8*)&fq[loff + kf*32];                             \
    f32x4 a0 = {bias[0],bias[0],bias[0],bias[0]};                              \
    f32x4 a1 = {bias[1],bias[1],bias[1],bias[1]};                              \
    f32x4 a2 = {bias[2],bias[2],bias[2],bias[2]};                              \
    f32x4 a3 = {bias[3],bias[3],bias[3],bias[3]};                              \
    _Pragma("unroll")                                                          \
    for (int kf = 0; kf < 4; ++kf) {                                           \
      a0 = mfma16(CUR[kf], bfr[0][kf], a0);                                    \
      a1 = mfma16(CUR[kf], bfr[1][kf], a1);                                    \
      a2 = mfma16(CUR[kf], bfr[2][kf], a2);                                    \
      a3 = mfma16(CUR[kf], bfr[3][kf], a3);                                    \
    }                                                                          \
    _Pragma("unroll")                                                          \
    for (int kf = 0; kf < 4; ++kf) {                                           \
      a0 = mfma16(hfr[kf], bfr[0][4+kf], a0);                                  \
      a1 = mfma16(hfr[kf], bfr[1][4+kf], a1);                                  \
      a2 = mfma16(hfr[kf], bfr[2][4+kf], a2);                                  \
      a3 = mfma16(hfr[kf], bfr[3][4+kf], a3);                                  \
    }                                                                          \
    float hnv[2], cnv[2];                                                      \
    _Pragma("unroll")                                                          \
    for (int j = 0; j < 2; ++j) {                                              \
      int rg = j*2;  /* C rows duplicated pairwise; even reg = valid copy */   \
      float si = __builtin_amdgcn_rcpf(1.0f + __builtin_amdgcn_exp2f(a0[rg])); \
      float sf = __builtin_amdgcn_rcpf(1.0f + __builtin_amdgcn_exp2f(a1[rg])); \
      float tg = __builtin_fmaf(2.0f,                                          \
                   __builtin_amdgcn_rcpf(1.0f + __builtin_amdgcn_exp2f(a2[rg])), -1.0f); \
      float so = __builtin_amdgcn_rcpf(1.0f + __builtin_amdgcn_exp2f(a3[rg])); \
      float cn = __builtin_fmaf(sf, cp[j], si*tg);                             \
      float th = __builtin_fmaf(2.0f,                                          \
                   __builtin_amdgcn_rcpf(1.0f + __builtin_amdgcn_exp2f(-2.0f*LOG2E*cn)), -1.0f); \
      hnv[j] = so * th;                                                        \
      cnv[j] = cn;                                                             \
    }                                                                          \
    uint32_t hpk = pk2(hnv[0], hnv[1]);                                        \
    unsigned short hu0 = (unsigned short)hpk;                                  \
    unsigned short hu1 = (unsigned short)(hpk >> 16);                          \
    int rbase = ((TTT) & 15) << 10;                                            \
    ring[rbase + hoffw[0]] = hu0;   /* unmasked h(t) for flush */              \
    ring[rbase + hoffw[1]] = hu1;                                              \
    float2 mn = *(const float2*)&mls[((TTT)+1)*8 + q*2];                       \
    bool l0 = (mn.x != 0.0f), l1 = (mn.y != 0.0f);                             \
    cp[0] = l0 ? cnv[0] : 0.0f; hp[0] = hnv[0];                                \
    cp[1] = l1 ? cnv[1] : 0.0f; hp[1] = hnv[1];                                \
    hlds[(HB)^1][hoffw[0]] = l0 ? hu0 : (unsigned short)0;                     \
    hlds[(HB)^1][hoffw[1]] = l1 ? hu1 : (unsigned short)0;                     \
    bar_lds();                                                                 \
  }

    for (int t = 0; t < TT; t += 2) {
      if (t && !(t & 7)) FLUSH(t - 8)
      LSTM_STEP(t,   afr, nfr, 0)
      LSTM_STEP(t+1, nfr, afr, 1)
    }
    FLUSH(TT - 8)
#undef LSTM_STEP
#undef FLUSH

    {
      float* outh = dout + (size_t)(4 + br*2) * NN;
      float* outc = dout + (size_t)(5 + br*2) * NN;
      #pragma unroll
      for (int j = 0; j < 2; ++j) {
        int b = base8 + q*2 + j;
        outh[b*HD + n] = hp[j];
        outc[b*HD + n] = cp[j];
      }
    }
  }

  // ================= Phase C: heads (GEMM actor / inline critic) =================
  if (tid == 0) flagS = 0;
  if (tid < HD) {
    pa[tid] = br ? clnw[tid] : alnw[tid];
    pb[tid] = br ? clnb[tid] : alnb[tid];
    if (br) cws[tid] = chw[tid];
  }
  int localf = 0;
  if (br == 0) {
    if (tid < NA) hbl[tid] = ahb[tid];
    for (int i = 2*tid + 1; i < 4096; i += 1024) localf |= action[i];
  } else if (tid == 0) cbsS = chb[0];
  __syncthreads();   // FULL: params visible; ring-flush stores drained before feat reads
  if (localf) flagS = 1;
  __syncthreads();

  int sub = tid & 3, kidx = tid >> 2;
  if (br == 0) {
    unsigned short* hsn = (unsigned short*)smemC;   // [128][128] bf16 swizzled
    float* co = (float*)(smemC + 32768);            // [128][36] f32
    // head B-frags: actions 0..17, zero-padded to 32 rows; pinned
    short8 hbf[2][4];
    #pragma unroll
    for (int nt = 0; nt < 2; ++nt) {
      int nn = nt*16 + ln;
      #pragma unroll
      for (int kf = 0; kf < 4; ++kf) {
        short8 z = {0,0,0,0,0,0,0,0};
        hbf[nt][kf] = (nn < NA) ? pin(cvt8(&ahw[nn*HD + kf*32 + q*8], 1.0f)) : z;
      }
    }
    int fl = flagS;
    for (int ch = 0; ch < 8; ++ch) {
      // --- stage A: LN (4 lanes/row) -> hsn bf16 swizzled ---
      {
        int k = ch*128 + kidx;
        int rrow = (k >> 3)*BB + base8 + (k & 7);
        const unsigned short* hp2 = feat + (size_t)rrow*HD + sub*32;
        uint4 d0 = *(const uint4*)hp2;
        uint4 d1 = *(const uint4*)(hp2 + 8);
        uint4 d2 = *(const uint4*)(hp2 + 16);
        uint4 d3 = *(const uint4*)(hp2 + 24);
        float nv[32];
        #define UP(W_, B_) { nv[B_] = bf2f((W_) & 0xffffu); nv[(B_)+1] = bf2f((W_) >> 16); }
        UP(d0.x,0) UP(d0.y,2) UP(d0.z,4) UP(d0.w,6)
        UP(d1.x,8) UP(d1.y,10) UP(d1.z,12) UP(d1.w,14)
        UP(d2.x,16) UP(d2.y,18) UP(d2.z,20) UP(d2.w,22)
        UP(d3.x,24) UP(d3.y,26) UP(d3.z,28) UP(d3.w,30)
        #undef UP
        float s = 0.0f, ssq = 0.0f;
        #pragma unroll
        for (int j = 0; j < 32; ++j) { s += nv[j]; ssq += nv[j]*nv[j]; }
        s += __shfl_xor(s, 1); ssq += __shfl_xor(ssq, 1);
        s += __shfl_xor(s, 2); ssq += __shfl_xor(ssq, 2);
        float mu = s * (1.0f/128.0f);
        float var = ssq * (1.0f/128.0f) - mu*mu;
        float rstd = rsqrtf(var + 1e-5f);
        #pragma unroll
        for (int cc = 0; cc < 4; ++cc) {
          float ov[8];
          #pragma unroll
          for (int j = 0; j < 8; ++j) {
            int c = sub*32 + cc*8 + j;
            ov[j] = (nv[cc*8+j] - mu) * rstd * pa[c] + pb[c];
          }
          uint4 P;
          P.x = pk2(ov[0], ov[1]); P.y = pk2(ov[2], ov[3]);
          P.z = pk2(ov[4], ov[5]); P.w = pk2(ov[6], ov[7]);
          int c8 = sub*4 + cc;
          *(uint4*)&hsn[kidx*128 + ((c8 ^ (kidx & 15)) << 3)] = P;
        }
      }
      bar_lds();
      // --- stage B: logits GEMM (wave w -> rows w*16..+16) ---
      {
        short8 afh[4];
        #pragma unroll
        for (int kf = 0; kf < 4; ++kf)
          afh[kf] = *(const short8*)&hsn[(w*16 + ln)*128 + ((((kf<<2)|q) ^ ln) << 3)];
        #pragma unroll
        for (int nt = 0; nt < 2; ++nt) {
          f32x4 acc = {0.0f, 0.0f, 0.0f, 0.0f};
          #pragma unroll
          for (int kf = 0; kf < 4; ++kf) acc = mfma16(afh[kf], hbf[nt][kf], acc);
          #pragma unroll
          for (int rg = 0; rg < 4; ++rg)
            co[(w*16 + q*4 + rg)*36 + nt*16 + ln] = acc[rg];
        }
      }
      bar_lds();
      // --- stage C: softmax/logp/entropy (1 thread/row, tid<128) ---
      if (tid < 128) {
        int k = ch*128 + tid;
        int rrow = (k >> 3)*BB + base8 + (k & 7);
        int act = fl ? action[rrow] : (int)(((const long long*)action)[rrow]);
        dout[rrow] = (float)act;
        int aidx = act < 0 ? 0 : (act > NA-1 ? NA-1 : act);
        float lg[NA];
        #pragma unroll
        for (int a = 0; a < NA; ++a) lg[a] = co[tid*36 + a] + hbl[a];
        float mx = lg[0];
        #pragma unroll
        for (int a = 1; a < NA; ++a) mx = fmaxf(mx, lg[a]);
        float se = 0.0f;
        #pragma unroll
        for (int a = 0; a < NA; ++a) se += __expf(lg[a] - mx);
        float lse = __logf(se);
        float lpa = 0.0f, ent = 0.0f;
        #pragma unroll
        for (int a = 0; a < NA; ++a) {
          float lp = lg[a] - mx - lse;
          ent -= __expf(lp) * lp;
          lpa += (a == aidx) ? lp : 0.0f;
        }
        dout[(size_t)NN + rrow] = lpa;
        dout[(size_t)2*NN + rrow] = ent;
      }
      bar_lds();
    }
  } else {
    // critic: inline LN + dot, no GEMM, no barriers needed
    for (int ch = 0; ch < 8; ++ch) {
      int k = ch*128 + kidx;
      int rrow = (k >> 3)*BB + base8 + (k & 3) + ((k & 7) - (k & 3));
      rrow = (k >> 3)*BB + base8 + (k & 7);
      const unsigned short* hp2 = feat + (size_t)rrow*HD + sub*32;
      uint4 d0 = *(const uint4*)hp2;
      uint4 d1 = *(const uint4*)(hp2 + 8);
      uint4 d2 = *(const uint4*)(hp2 + 16);
      uint4 d3 = *(const uint4*)(hp2 + 24);
      float nv[32];
      #define UP(W_, B_) { nv[B_] = bf2f((W_) & 0xffffu); nv[(B_)+1] = bf2f((W_) >> 16); }
      UP(d0.x,0) UP(d0.y,2) UP(d0.z,4) UP(d0.w,6)
      UP(d1.x,8) UP(d1.y,10) UP(d1.z,12) UP(d1.w,14)
      UP(d2.x,16) UP(d2.y,18) UP(d2.z,20) UP(d2.w,22)
      UP(d3.x,24) UP(d3.y,26) UP(d3.z,28) UP(d3.w,30)
      #undef UP
      float s = 0.0f, ssq = 0.0f;
      #pragma unroll
      for (int j = 0; j < 32; ++j) { s += nv[j]; ssq += nv[j]*nv[j]; }
      s += __shfl_xor(s, 1); ssq += __shfl_xor(ssq, 1);
      s += __shfl_xor(s, 2); ssq += __shfl_xor(ssq, 2);
      float mu = s * (1.0f/128.0f);
      float var = ssq * (1.0f/128.0f) - mu*mu;
      float rstd = rsqrtf(var + 1e-5f);
      float dot = 0.0f;
      #pragma unroll
      for (int j = 0; j < 32; ++j) {
        int c = sub*32 + j;
        dot += ((nv[j] - mu) * rstd * pa[c] + pb[c]) * cws[c];
      }
      dot += __shfl_xor(dot, 1);
      dot += __shfl_xor(dot, 2);
      if (sub == 0) dout[(size_t)3*NN + rrow] = dot + cbsS;
    }
  }
}

extern "C" void kernel_launch(void* const* d_in, const int* in_sizes, int n_in,
                              void* d_out, int out_size, void* d_ws, size_t ws_size,
                              hipStream_t stream) {
  (void)in_sizes; (void)n_in; (void)out_size; (void)ws_size;
  const float* x    = (const float*)d_in[0];
  const float* ah0  = (const float*)d_in[1];
  const float* ac0  = (const float*)d_in[2];
  const float* ch0  = (const float*)d_in[3];
  const float* cc0  = (const float*)d_in[4];
  const int*   done = (const int*)d_in[5];
  const int*   act  = (const int*)d_in[6];
  const float* aw1  = (const float*)d_in[7];
  const float* ab1  = (const float*)d_in[8];
  const float* aw2  = (const float*)d_in[9];
  const float* ab2  = (const float*)d_in[10];
  const float* aflnw= (const float*)d_in[11];
  const float* aflnb= (const float*)d_in[12];
  const float* awih = (const float*)d_in[13];
  const float* awhh = (const float*)d_in[14];
  const float* a_b  = (const float*)d_in[15];
  const float* alnw = (const float*)d_in[16];
  const float* alnb = (const float*)d_in[17];
  const float* ahw  = (const float*)d_in[18];
  const float* ahb  = (const float*)d_in[19];
  const float* cw1  = (const float*)d_in[20];
  const float* cb1  = (const float*)d_in[21];
  const float* cw2  = (const float*)d_in[22];
  const float* cb2  = (const float*)d_in[23];
  const float* cflnw= (const float*)d_in[24];
  const float* cflnb= (const float*)d_in[25];
  const float* cwih = (const float*)d_in[26];
  const float* cwhh = (const float*)d_in[27];
  const float* c_b  = (const float*)d_in[28];
  const float* clnw = (const float*)d_in[29];
  const float* clnb = (const float*)d_in[30];
  const float* chw  = (const float*)d_in[31];
  const float* chb  = (const float*)d_in[32];

  unsigned short* featb = (unsigned short*)d_ws;   // [2][NN*HD] bf16
  float* out = (float*)d_out;

  feat_kernel<<<256, 512, 0, stream>>>(
      x, aw1, ab1, aw2, ab2, aflnw, aflnb,
      cw1, cb1, cw2, cb2, cflnw, cflnb, featb);

  lstm_head_kernel<<<256, 512, 0, stream>>>(
      done, act,
      awih, awhh, a_b, alnw, alnb, ahw, ahb,
      cwih, cwhh, c_b, clnw, clnb, chw, chb,
      ah0, ac0, ch0, cc0,
      featb, out);
}

// Round 4
// 431.719 us; speedup vs baseline: 1.0193x; 1.0193x over previous
//
#include <hip/hip_runtime.h>
#include <stdint.h>
#include <stddef.h>

#define OBS 128
#define F1D 256
#define HD  128
#define NA  18
#define TT  128
#define BB  1024
#define NN  (TT*BB)
#define LOG2E 1.442695041f

typedef __attribute__((ext_vector_type(8))) short short8;
typedef __attribute__((ext_vector_type(4))) float f32x4;

__device__ __forceinline__ unsigned short f2bf(float f) {
  union { float f; uint32_t u; } v; v.f = f;
  uint32_t u = v.u;
  u += 0x7fffu + ((u >> 16) & 1u);   // RNE
  return (unsigned short)(u >> 16);
}
__device__ __forceinline__ float bf2f(uint32_t hu) {
  union { uint32_t u; float f; } v; v.u = hu << 16;
  return v.f;
}
// packed bf16 convert — v_cvt_pk_bf16_f32 (RNE), 1 instr for 2 values.
__device__ __forceinline__ uint32_t pk2(float lo, float hi) {
  uint32_t r;
  asm("v_cvt_pk_bf16_f32 %0, %1, %2" : "=v"(r) : "v"(lo), "v"(hi));
  return r;
}
__device__ __forceinline__ f32x4 mfma16(short8 a, short8 b, f32x4 c) {
  return __builtin_amdgcn_mfma_f32_16x16x32_bf16(a, b, c, 0, 0, 0);
}
// f32 -> bf16 fragment (8 consecutive, scaled) via packed converts
__device__ __forceinline__ short8 cvt8(const float* p, float sc) {
  float4 a = *(const float4*)p;
  float4 b = *(const float4*)(p + 4);
  union { uint32_t u[4]; short8 s; } o;
  o.u[0] = pk2(a.x*sc, a.y*sc);
  o.u[1] = pk2(a.z*sc, a.w*sc);
  o.u[2] = pk2(b.x*sc, b.y*sc);
  o.u[3] = pk2(b.z*sc, b.w*sc);
  return o.s;
}
// pin: empty volatile asm with tied SCALAR "+v" operands (R6/R7 lessons).
__device__ __forceinline__ short8 pin(short8 v) {
  int4 i = *(int4*)&v;
  asm volatile("" : "+v"(i.x), "+v"(i.y), "+v"(i.z), "+v"(i.w));
  return *(short8*)&i;
}

// ================= Kernel A: feature MLP (both branches) =================
// Unchanged from R11.
__global__ __launch_bounds__(512, 2) void feat_kernel(
    const float* __restrict__ x,
    const float* __restrict__ aw1, const float* __restrict__ ab1,
    const float* __restrict__ aw2, const float* __restrict__ ab2,
    const float* __restrict__ aflnw, const float* __restrict__ aflnb,
    const float* __restrict__ cw1, const float* __restrict__ cb1,
    const float* __restrict__ cw2, const float* __restrict__ cb2,
    const float* __restrict__ cflnw, const float* __restrict__ cflnb,
    unsigned short* __restrict__ featg)
{
  int g = blockIdx.x;
  int br = g >> 7;
  int chunk = g & 127;
  int base8 = chunk * 8;

  const float* w1  = br ? cw1 : aw1;     // [256][128]
  const float* b1  = br ? cb1 : ab1;
  const float* w2  = br ? cw2 : aw2;     // [128][256]
  const float* b2  = br ? cb2 : ab2;
  const float* flw = br ? cflnw : aflnw;
  const float* flb = br ? cflnb : aflnb;
  unsigned short* feat = featg + (size_t)br * NN * HD;

  __shared__ __align__(16) char smemA[51200];  // xs(16K)+h1s(32K)+lnsum(2K)

  int tid = threadIdx.x;
  int w = tid >> 6, lane = tid & 63, q = lane >> 4, ln = lane & 15;
  int team = tid >> 8, t_tid = tid & 255, w4 = w & 3;

  unsigned short* xst  = (unsigned short*)smemA + team*4096;           // 32*128
  unsigned short* h1st = (unsigned short*)(smemA + 16384) + team*8192; // 32*256
  float*          lnst = (float*)(smemA + 49152) + team*256;           // 32*8

  short8 b1f[4][4]; float b1v[4];
  #pragma unroll
  for (int ct = 0; ct < 4; ++ct) {
    int nn = w4*64 + ct*16 + ln;
    b1v[ct] = b1[nn];
    #pragma unroll
    for (int kf = 0; kf < 4; ++kf)
      b1f[ct][kf] = pin(cvt8(&w1[nn*OBS + kf*32 + q*8], 1.0f));
  }
  short8 b2f[2][8]; float b2v[2], lwv[2], lbv[2];
  #pragma unroll
  for (int nt = 0; nt < 2; ++nt) {
    int nn = w4*32 + nt*16 + ln;
    b2v[nt] = b2[nn]; lwv[nt] = flw[nn]; lbv[nt] = flb[nn];
    #pragma unroll
    for (int kf = 0; kf < 8; ++kf)
      b2f[nt][kf] = pin(cvt8(&w2[nn*F1D + kf*32 + q*8], 1.0f));
  }
  // tile = 4 timesteps x 8 batch rows = 32 rows; team handles tiles 2j+team
  float4 xr[4];
  #pragma unroll
  for (int s = 0; s < 4; ++s) {
    int e4 = t_tid + s*256;
    int r = e4 >> 5, c4 = e4 & 31;
    size_t grow = (size_t)(team*4 + (r>>3))*BB + base8 + (r&7);
    xr[s] = ((const float4*)x)[grow*32 + c4];
  }
  for (int j = 0; j < 16; ++j) {
    int jj = j*2 + team;
    #pragma unroll
    for (int s = 0; s < 4; ++s) {
      int e = (t_tid + s*256) * 4;
      int r = e >> 7, k = e & 127;
      int ad = r*128 + ((((k>>3) ^ (r&15)) << 3)) + (k&7);
      uint2 d;
      d.x = pk2(xr[s].x, xr[s].y);
      d.y = pk2(xr[s].z, xr[s].w);
      *(uint2*)&xst[ad] = d;
    }
    __syncthreads();                 // B1: xs ready
    {
      int jjn = (j < 15) ? jj + 2 : jj;
      #pragma unroll
      for (int s = 0; s < 4; ++s) {
        int e4 = t_tid + s*256;
        int r = e4 >> 5, c4 = e4 & 31;
        size_t grow = (size_t)(jjn*4 + (r>>3))*BB + base8 + (r&7);
        xr[s] = ((const float4*)x)[grow*32 + c4];
      }
    }
    // ---- G1 ----
    short8 af[2][4];
    #pragma unroll
    for (int mt = 0; mt < 2; ++mt)
      #pragma unroll
      for (int kf = 0; kf < 4; ++kf)
        af[mt][kf] = *(const short8*)&xst[(mt*16 + ln)*128 + ((((kf<<2)|q) ^ ln) << 3)];
    #pragma unroll
    for (int ct = 0; ct < 4; ++ct) {
      int nn = w4*64 + ct*16 + ln;
      #pragma unroll
      for (int mt = 0; mt < 2; ++mt) {
        f32x4 acc = {b1v[ct], b1v[ct], b1v[ct], b1v[ct]};
        #pragma unroll
        for (int kf = 0; kf < 4; ++kf) acc = mfma16(af[mt][kf], b1f[ct][kf], acc);
        float v0 = acc[0] > 0.0f ? acc[0] : 0.0f;
        float v1 = acc[1] > 0.0f ? acc[1] : 0.0f;
        float v2 = acc[2] > 0.0f ? acc[2] : 0.0f;
        float v3 = acc[3] > 0.0f ? acc[3] : 0.0f;
        uint32_t p01 = pk2(v0, v1), p23 = pk2(v2, v3);
        int r0 = mt*16 + q*4;
        h1st[(r0+0)*256 + (((nn>>3) ^ ((r0+0)&15)) << 3) + (nn&7)] = (unsigned short)p01;
        h1st[(r0+1)*256 + (((nn>>3) ^ ((r0+1)&15)) << 3) + (nn&7)] = (unsigned short)(p01 >> 16);
        h1st[(r0+2)*256 + (((nn>>3) ^ ((r0+2)&15)) << 3) + (nn&7)] = (unsigned short)p23;
        h1st[(r0+3)*256 + (((nn>>3) ^ ((r0+3)&15)) << 3) + (nn&7)] = (unsigned short)(p23 >> 16);
      }
    }
    __syncthreads();                 // B2: h1s ready
    // ---- G2 ----
    f32x4 acc2[2][2];
    #pragma unroll
    for (int mt = 0; mt < 2; ++mt) {
      short8 ah[8];
      #pragma unroll
      for (int kf = 0; kf < 8; ++kf)
        ah[kf] = *(const short8*)&h1st[(mt*16 + ln)*256 + ((((kf<<2)|q) ^ ln) << 3)];
      #pragma unroll
      for (int nt = 0; nt < 2; ++nt) {
        f32x4 acc = {b2v[nt], b2v[nt], b2v[nt], b2v[nt]};
        #pragma unroll
        for (int kf = 0; kf < 8; ++kf) acc = mfma16(ah[kf], b2f[nt][kf], acc);
        acc2[nt][mt] = acc;
      }
    }
    // ---- LN partials ----
    #pragma unroll
    for (int mt = 0; mt < 2; ++mt)
      #pragma unroll
      for (int rg = 0; rg < 4; ++rg) {
        float s = acc2[0][mt][rg] + acc2[1][mt][rg];
        float ssq = acc2[0][mt][rg]*acc2[0][mt][rg] + acc2[1][mt][rg]*acc2[1][mt][rg];
        #pragma unroll
        for (int m = 1; m < 16; m <<= 1) { s += __shfl_xor(s, m); ssq += __shfl_xor(ssq, m); }
        if (ln == 0) {
          int r = mt*16 + q*4 + rg;
          lnst[r*8 + w4*2]     = s;
          lnst[r*8 + w4*2 + 1] = ssq;
        }
      }
    __syncthreads();                 // B3: lnsum ready
    #pragma unroll
    for (int mt = 0; mt < 2; ++mt)
      #pragma unroll
      for (int rg = 0; rg < 4; ++rg) {
        int r = mt*16 + q*4 + rg;
        float4 p0 = *(const float4*)&lnst[r*8];
        float4 p1 = *(const float4*)&lnst[r*8 + 4];
        float S  = p0.x + p0.z + p1.x + p1.z;
        float SS = p0.y + p0.w + p1.y + p1.w;
        float mu = S * (1.0f/128.0f);
        float var = SS * (1.0f/128.0f) - mu*mu;
        float rstd = rsqrtf(var + 1e-5f);
        size_t grow = (size_t)(jj*4 + (r>>3))*BB + base8 + (r&7);
        float t0 = (acc2[0][mt][rg] - mu) * rstd * lwv[0] + lbv[0];
        float t1 = (acc2[1][mt][rg] - mu) * rstd * lwv[1] + lbv[1];
        if (t0 < 0.0f) t0 = 0.0f;
        if (t1 < 0.0f) t1 = 0.0f;
        uint32_t p = pk2(t0, t1);
        unsigned short* fp = &feat[grow*HD + w4*32 + ln];
        fp[0]  = (unsigned short)p;
        fp[16] = (unsigned short)(p >> 16);
      }
    __syncthreads();                 // Bend
  }
}

// ================= Kernel BC: masked LSTM + heads =================
// R13: software-pipelined LSTM step. Step t finishes its gates with the 16
// h-MFMAs (XA), then ISSUES step t+1's 16 x-MFMAs (XN: bias + feat[t+1]@Wih)
// before the sigmoid tail — the x-work of the next step fills the matrix
// pipe while this step's transcendental tail + barrier wait run. The x-part
// has no dependence on h(t), and per-gate FP order (bias, x kf0..3, h kf0..3)
// is unchanged, so results are bit-identical. Store/barrier structure = R11
// (per-step 2B stores + full __syncthreads; R10/R12 drain experiments both
// regressed — the drain was never the bottleneck, pipe underfeed was).
__global__ __launch_bounds__(512, 2) void lstm_head_kernel(
    const int* __restrict__ done, const int* __restrict__ action,
    const float* __restrict__ awih, const float* __restrict__ awhh,
    const float* __restrict__ a_b,
    const float* __restrict__ alnw, const float* __restrict__ alnb,
    const float* __restrict__ ahw, const float* __restrict__ ahb,
    const float* __restrict__ cwih, const float* __restrict__ cwhh,
    const float* __restrict__ c_b,
    const float* __restrict__ clnw, const float* __restrict__ clnb,
    const float* __restrict__ chw, const float* __restrict__ chb,
    const float* __restrict__ ah0, const float* __restrict__ ac0,
    const float* __restrict__ ch0, const float* __restrict__ cc0,
    unsigned short* __restrict__ featg, float* __restrict__ dout)
{
  int g = blockIdx.x;
  int br = g >> 7;
  int chunk = g & 127;
  int base8 = chunk * 8;

  const float* wih = br ? cwih : awih;   // [512][128]
  const float* whh = br ? cwhh : awhh;
  const float* gb  = br ? c_b : a_b;
  const float* h0  = br ? ch0 : ah0;
  const float* c0  = br ? cc0 : ac0;
  unsigned short* feat = featg + (size_t)br * NN * HD;

  __shared__ __align__(16) char smemC[51200];  // Phase C: hsn(32K)+cout(18K)
  __shared__ float mls[(TT+1)*8];              // 1 - done, padded t=TT
  __shared__ unsigned short hlds[2][8*128];    // double-buffered masked h
  __shared__ float pa[HD], pb[HD], cws[HD];
  __shared__ float hbl[NA];
  __shared__ float cbsS;
  __shared__ int flagS;

  int tid = threadIdx.x;
  int w = tid >> 6, lane = tid & 63, q = lane >> 4, ln = lane & 15;

  // ================= Phase B: masked LSTM (M=8, stride-2 packing) =================
  int n = w*16 + ln;
  {
    short8 bfr[4][8]; float bias[4];
    #pragma unroll
    for (int g4 = 0; g4 < 4; ++g4) {
      int gn = g4*128 + n;
      float sc = (g4 == 2) ? -2.0f*LOG2E : -LOG2E;   // gate order i,f,g,o
      bias[g4] = gb[gn] * sc;
      #pragma unroll
      for (int kf = 0; kf < 8; ++kf) {
        const float* src = (kf < 4) ? &wih[gn*HD + kf*32 + q*8]
                                    : &whh[gn*HD + (kf-4)*32 + q*8];
        bfr[g4][kf] = pin(cvt8(src, sc));
      }
    }
    for (int i = tid; i < (TT+1)*8; i += 512)
      mls[i] = (i < TT*8) ? 1.0f - (float)done[(i>>3)*BB + base8 + (i&7)] : 1.0f;

    const int loff = (base8 + (ln>>1))*HD + q*8;   // A-row ln -> batch row ln>>1
    int soff[2], hoffw[2], haddr[4];
    #pragma unroll
    for (int j = 0; j < 2; ++j) {
      int r = q*2 + j;
      soff[j]  = (base8 + r)*HD + n;
      hoffw[j] = r*128 + (((n>>3) ^ r) << 3) + (n&7);
    }
    #pragma unroll
    for (int kf = 0; kf < 4; ++kf) {
      int rr = ln >> 1;
      haddr[kf] = rr*128 + ((((kf<<2)|q) ^ rr) << 3);
    }
    float hp[2], cp[2]; unsigned short hu_prev[2];
    #pragma unroll
    for (int j = 0; j < 2; ++j) {
      int b = base8 + q*2 + j;
      hp[j] = h0[b*HD + n];
      cp[j] = c0[b*HD + n];
      hu_prev[j] = 0;
    }
    __syncthreads();   // mls ready (feat visible via kernel boundary)

    // Pipeline prologue: gates(0) x-part from feat[0]; f1 = feat[1].
    short8 f0[4], f1[4];
    #pragma unroll
    for (int kf = 0; kf < 4; ++kf)
      f0[kf] = *(const short8*)&feat[loff + kf*32];          // feat[0]
    f32x4 xgA[4], xgB[4];
    #pragma unroll
    for (int g4 = 0; g4 < 4; ++g4)
      xgA[g4] = (f32x4){bias[g4], bias[g4], bias[g4], bias[g4]};
    #pragma unroll
    for (int kf = 0; kf < 4; ++kf) {
      xgA[0] = mfma16(f0[kf], bfr[0][kf], xgA[0]);
      xgA[1] = mfma16(f0[kf], bfr[1][kf], xgA[1]);
      xgA[2] = mfma16(f0[kf], bfr[2][kf], xgA[2]);
      xgA[3] = mfma16(f0[kf], bfr[3][kf], xgA[3]);
    }
    {
      const unsigned short* fq1 = feat + (size_t)1 * (BB*HD);
      #pragma unroll
      for (int kf = 0; kf < 4; ++kf)
        f1[kf] = *(const short8*)&fq1[loff + kf*32];         // feat[1]
    }
    {
      float m0 = mls[q*2], m1 = mls[q*2 + 1];
      cp[0] *= m0; cp[1] *= m1;
      uint32_t hpk = pk2(hp[0]*m0, hp[1]*m1);
      hlds[0][hoffw[0]] = (unsigned short)hpk;
      hlds[0][hoffw[1]] = (unsigned short)(hpk >> 16);
    }
    __syncthreads();   // hlds[0] ready

// Step TTT: XA holds bias + x-part of gates(TTT); CUR = feat[TTT+1] frags.
// Finishes XA with h-MFMAs, issues XN = bias + x-part(TTT+1) from CUR,
// prefetches NXT = feat[TTT+2], then sigmoid tail on XA.
#define LSTM_STEP(TTT, CUR, NXT, XA, XN, HB)                                   \
  {                                                                            \
    short8 hfr[4];                                                             \
    _Pragma("unroll")                                                          \
    for (int kf = 0; kf < 4; ++kf)                                             \
      hfr[kf] = *(const short8*)&hlds[HB][haddr[kf]];                          \
    if ((TTT) > 0) {                                                           \
      unsigned short* sq = feat + (size_t)((TTT) - 1) * (BB*HD);               \
      sq[soff[0]] = hu_prev[0];                                                \
      sq[soff[1]] = hu_prev[1];                                                \
    }                                                                          \
    int tn = ((TTT) + 2 < TT) ? (TTT) + 2 : TT - 1;                            \
    const unsigned short* fq = feat + (size_t)tn * (BB*HD);                    \
    _Pragma("unroll")                                                          \
    for (int kf = 0; kf < 4; ++kf)                                             \
      NXT[kf] = *(const short8*)&fq[loff + kf*32];                             \
    _Pragma("unroll")                                                          \
    for (int kf = 0; kf < 4; ++kf) {                                           \
      (XA)[0] = mfma16(hfr[kf], bfr[0][4+kf], (XA)[0]);                        \
      (XA)[1] = mfma16(hfr[kf], bfr[1][4+kf], (XA)[1]);                        \
      (XA)[2] = mfma16(hfr[kf], bfr[2][4+kf], (XA)[2]);                        \
      (XA)[3] = mfma16(hfr[kf], bfr[3][4+kf], (XA)[3]);                        \
    }                                                                          \
    (XN)[0] = (f32x4){bias[0], bias[0], bias[0], bias[0]};                     \
    (XN)[1] = (f32x4){bias[1], bias[1], bias[1], bias[1]};                     \
    (XN)[2] = (f32x4){bias[2], bias[2], bias[2], bias[2]};                     \
    (XN)[3] = (f32x4){bias[3], bias[3], bias[3], bias[3]};                     \
    _Pragma("unroll")                                                          \
    for (int kf = 0; kf < 4; ++kf) {                                           \
      (XN)[0] = mfma16(CUR[kf], bfr[0][kf], (XN)[0]);                          \
      (XN)[1] = mfma16(CUR[kf], bfr[1][kf], (XN)[1]);                          \
      (XN)[2] = mfma16(CUR[kf], bfr[2][kf], (XN)[2]);                          \
      (XN)[3] = mfma16(CUR[kf], bfr[3][kf], (XN)[3]);                          \
    }                                                                          \
    float hnv[2], cnv[2];                                                      \
    _Pragma("unroll")                                                          \
    for (int j = 0; j < 2; ++j) {                                              \
      int rg = j*2;  /* C rows duplicated pairwise; even reg = valid copy */   \
      float si = __builtin_amdgcn_rcpf(1.0f + __builtin_amdgcn_exp2f((XA)[0][rg])); \
      float sf = __builtin_amdgcn_rcpf(1.0f + __builtin_amdgcn_exp2f((XA)[1][rg])); \
      float tg = __builtin_fmaf(2.0f,                                          \
                   __builtin_amdgcn_rcpf(1.0f + __builtin_amdgcn_exp2f((XA)[2][rg])), -1.0f); \
      float so = __builtin_amdgcn_rcpf(1.0f + __builtin_amdgcn_exp2f((XA)[3][rg])); \
      float cn = __builtin_fmaf(sf, cp[j], si*tg);                             \
      float th = __builtin_fmaf(2.0f,                                          \
                   __builtin_amdgcn_rcpf(1.0f + __builtin_amdgcn_exp2f(-2.0f*LOG2E*cn)), -1.0f); \
      hnv[j] = so * th;                                                        \
      cnv[j] = cn;                                                             \
    }                                                                          \
    uint32_t hpk = pk2(hnv[0], hnv[1]);                                        \
    unsigned short hu0 = (unsigned short)hpk;                                  \
    unsigned short hu1 = (unsigned short)(hpk >> 16);                          \
    hu_prev[0] = hu0; hu_prev[1] = hu1;                                        \
    float2 mn = *(const float2*)&mls[((TTT)+1)*8 + q*2];                       \
    bool l0 = (mn.x != 0.0f), l1 = (mn.y != 0.0f);                             \
    cp[0] = l0 ? cnv[0] : 0.0f; hp[0] = hnv[0];                                \
    cp[1] = l1 ? cnv[1] : 0.0f; hp[1] = hnv[1];                                \
    hlds[(HB)^1][hoffw[0]] = l0 ? hu0 : (unsigned short)0;                     \
    hlds[(HB)^1][hoffw[1]] = l1 ? hu1 : (unsigned short)0;                     \
    __syncthreads();                                                           \
  }

    for (int t = 0; t < TT; t += 2) {
      LSTM_STEP(t,   f1, f0, xgA, xgB, 0)
      LSTM_STEP(t+1, f0, f1, xgB, xgA, 1)
    }
#undef LSTM_STEP

    {
      unsigned short* sq = feat + (size_t)(TT-1)*(BB*HD);
      sq[soff[0]] = hu_prev[0];
      sq[soff[1]] = hu_prev[1];
    }
    {
      float* outh = dout + (size_t)(4 + br*2) * NN;
      float* outc = dout + (size_t)(5 + br*2) * NN;
      #pragma unroll
      for (int j = 0; j < 2; ++j) {
        int b = base8 + q*2 + j;
        outh[b*HD + n] = hp[j];
        outc[b*HD + n] = cp[j];
      }
    }
  }

  // ================= Phase C: heads (GEMM actor / inline critic) =================
  if (tid == 0) flagS = 0;
  if (tid < HD) {
    pa[tid] = br ? clnw[tid] : alnw[tid];
    pb[tid] = br ? clnb[tid] : alnb[tid];
    if (br) cws[tid] = chw[tid];
  }
  int localf = 0;
  if (br == 0) {
    if (tid < NA) hbl[tid] = ahb[tid];
    for (int i = 2*tid + 1; i < 4096; i += 1024) localf |= action[i];
  } else if (tid == 0) cbsS = chb[0];
  __syncthreads();   // params + flagS=0 visible; hs stores drained
  if (localf) flagS = 1;
  __syncthreads();

  int sub = tid & 3, kidx = tid >> 2;
  if (br == 0) {
    unsigned short* hsn = (unsigned short*)smemC;   // [128][128] bf16 swizzled
    float* co = (float*)(smemC + 32768);            // [128][36] f32
    // head B-frags: actions 0..17, zero-padded to 32 rows; pinned
    short8 hbf[2][4];
    #pragma unroll
    for (int nt = 0; nt < 2; ++nt) {
      int nn = nt*16 + ln;
      #pragma unroll
      for (int kf = 0; kf < 4; ++kf) {
        short8 z = {0,0,0,0,0,0,0,0};
        hbf[nt][kf] = (nn < NA) ? pin(cvt8(&ahw[nn*HD + kf*32 + q*8], 1.0f)) : z;
      }
    }
    int fl = flagS;
    for (int ch = 0; ch < 8; ++ch) {
      // --- stage A: LN (4 lanes/row) -> hsn bf16 swizzled ---
      {
        int k = ch*128 + kidx;
        int rrow = (k >> 3)*BB + base8 + (k & 7);
        const unsigned short* hp2 = feat + (size_t)rrow*HD + sub*32;
        uint4 d0 = *(const uint4*)hp2;
        uint4 d1 = *(const uint4*)(hp2 + 8);
        uint4 d2 = *(const uint4*)(hp2 + 16);
        uint4 d3 = *(const uint4*)(hp2 + 24);
        float nv[32];
        #define UP(W_, B_) { nv[B_] = bf2f((W_) & 0xffffu); nv[(B_)+1] = bf2f((W_) >> 16); }
        UP(d0.x,0) UP(d0.y,2) UP(d0.z,4) UP(d0.w,6)
        UP(d1.x,8) UP(d1.y,10) UP(d1.z,12) UP(d1.w,14)
        UP(d2.x,16) UP(d2.y,18) UP(d2.z,20) UP(d2.w,22)
        UP(d3.x,24) UP(d3.y,26) UP(d3.z,28) UP(d3.w,30)
        #undef UP
        float s = 0.0f, ssq = 0.0f;
        #pragma unroll
        for (int j = 0; j < 32; ++j) { s += nv[j]; ssq += nv[j]*nv[j]; }
        s += __shfl_xor(s, 1); ssq += __shfl_xor(ssq, 1);
        s += __shfl_xor(s, 2); ssq += __shfl_xor(ssq, 2);
        float mu = s * (1.0f/128.0f);
        float var = ssq * (1.0f/128.0f) - mu*mu;
        float rstd = rsqrtf(var + 1e-5f);
        #pragma unroll
        for (int cc = 0; cc < 4; ++cc) {
          float ov[8];
          #pragma unroll
          for (int j = 0; j < 8; ++j) {
            int c = sub*32 + cc*8 + j;
            ov[j] = (nv[cc*8+j] - mu) * rstd * pa[c] + pb[c];
          }
          uint4 P;
          P.x = pk2(ov[0], ov[1]); P.y = pk2(ov[2], ov[3]);
          P.z = pk2(ov[4], ov[5]); P.w = pk2(ov[6], ov[7]);
          int c8 = sub*4 + cc;
          *(uint4*)&hsn[kidx*128 + ((c8 ^ (kidx & 15)) << 3)] = P;
        }
      }
      __syncthreads();
      // --- stage B: logits GEMM (wave w -> rows w*16..+16) ---
      {
        short8 afh[4];
        #pragma unroll
        for (int kf = 0; kf < 4; ++kf)
          afh[kf] = *(const short8*)&hsn[(w*16 + ln)*128 + ((((kf<<2)|q) ^ ln) << 3)];
        #pragma unroll
        for (int nt = 0; nt < 2; ++nt) {
          f32x4 acc = {0.0f, 0.0f, 0.0f, 0.0f};
          #pragma unroll
          for (int kf = 0; kf < 4; ++kf) acc = mfma16(afh[kf], hbf[nt][kf], acc);
          #pragma unroll
          for (int rg = 0; rg < 4; ++rg)
            co[(w*16 + q*4 + rg)*36 + nt*16 + ln] = acc[rg];
        }
      }
      __syncthreads();
      // --- stage C: softmax/logp/entropy (1 thread/row, tid<128) ---
      if (tid < 128) {
        int k = ch*128 + tid;
        int rrow = (k >> 3)*BB + base8 + (k & 7);
        int act = fl ? action[rrow] : (int)(((const long long*)action)[rrow]);
        dout[rrow] = (float)act;
        int aidx = act < 0 ? 0 : (act > NA-1 ? NA-1 : act);
        float lg[NA];
        #pragma unroll
        for (int a = 0; a < NA; ++a) lg[a] = co[tid*36 + a] + hbl[a];
        float mx = lg[0];
        #pragma unroll
        for (int a = 1; a < NA; ++a) mx = fmaxf(mx, lg[a]);
        float se = 0.0f;
        #pragma unroll
        for (int a = 0; a < NA; ++a) se += __expf(lg[a] - mx);
        float lse = __logf(se);
        float lpa = 0.0f, ent = 0.0f;
        #pragma unroll
        for (int a = 0; a < NA; ++a) {
          float lp = lg[a] - mx - lse;
          ent -= __expf(lp) * lp;
          lpa += (a == aidx) ? lp : 0.0f;
        }
        dout[(size_t)NN + rrow] = lpa;
        dout[(size_t)2*NN + rrow] = ent;
      }
      __syncthreads();
    }
  } else {
    // critic: inline LN + dot, no GEMM, no barriers needed
    for (int ch = 0; ch < 8; ++ch) {
      int k = ch*128 + kidx;
      int rrow = (k >> 3)*BB + base8 + (k & 7);
      const unsigned short* hp2 = feat + (size_t)rrow*HD + sub*32;
      uint4 d0 = *(const uint4*)hp2;
      uint4 d1 = *(const uint4*)(hp2 + 8);
      uint4 d2 = *(const uint4*)(hp2 + 16);
      uint4 d3 = *(const uint4*)(hp2 + 24);
      float nv[32];
      #define UP(W_, B_) { nv[B_] = bf2f((W_) & 0xffffu); nv[(B_)+1] = bf2f((W_) >> 16); }
      UP(d0.x,0) UP(d0.y,2) UP(d0.z,4) UP(d0.w,6)
      UP(d1.x,8) UP(d1.y,10) UP(d1.z,12) UP(d1.w,14)
      UP(d2.x,16) UP(d2.y,18) UP(d2.z,20) UP(d2.w,22)
      UP(d3.x,24) UP(d3.y,26) UP(d3.z,28) UP(d3.w,30)
      #undef UP
      float s = 0.0f, ssq = 0.0f;
      #pragma unroll
      for (int j = 0; j < 32; ++j) { s += nv[j]; ssq += nv[j]*nv[j]; }
      s += __shfl_xor(s, 1); ssq += __shfl_xor(ssq, 1);
      s += __shfl_xor(s, 2); ssq += __shfl_xor(ssq, 2);
      float mu = s * (1.0f/128.0f);
      float var = ssq * (1.0f/128.0f) - mu*mu;
      float rstd = rsqrtf(var + 1e-5f);
      float dot = 0.0f;
      #pragma unroll
      for (int j = 0; j < 32; ++j) {
        int c = sub*32 + j;
        dot += ((nv[j] - mu) * rstd * pa[c] + pb[c]) * cws[c];
      }
      dot += __shfl_xor(dot, 1);
      dot += __shfl_xor(dot, 2);
      if (sub == 0) dout[(size_t)3*NN + rrow] = dot + cbsS;
    }
  }
}

extern "C" void kernel_launch(void* const* d_in, const int* in_sizes, int n_in,
                              void* d_out, int out_size, void* d_ws, size_t ws_size,
                              hipStream_t stream) {
  (void)in_sizes; (void)n_in; (void)out_size; (void)ws_size;
  const float* x    = (const float*)d_in[0];
  const float* ah0  = (const float*)d_in[1];
  const float* ac0  = (const float*)d_in[2];
  const float* ch0  = (const float*)d_in[3];
  const float* cc0  = (const float*)d_in[4];
  const int*   done = (const int*)d_in[5];
  const int*   act  = (const int*)d_in[6];
  const float* aw1  = (const float*)d_in[7];
  const float* ab1  = (const float*)d_in[8];
  const float* aw2  = (const float*)d_in[9];
  const float* ab2  = (const float*)d_in[10];
  const float* aflnw= (const float*)d_in[11];
  const float* aflnb= (const float*)d_in[12];
  const float* awih = (const float*)d_in[13];
  const float* awhh = (const float*)d_in[14];
  const float* a_b  = (const float*)d_in[15];
  const float* alnw = (const float*)d_in[16];
  const float* alnb = (const float*)d_in[17];
  const float* ahw  = (const float*)d_in[18];
  const float* ahb  = (const float*)d_in[19];
  const float* cw1  = (const float*)d_in[20];
  const float* cb1  = (const float*)d_in[21];
  const float* cw2  = (const float*)d_in[22];
  const float* cb2  = (const float*)d_in[23];
  const float* cflnw= (const float*)d_in[24];
  const float* cflnb= (const float*)d_in[25];
  const float* cwih = (const float*)d_in[26];
  const float* cwhh = (const float*)d_in[27];
  const float* c_b  = (const float*)d_in[28];
  const float* clnw = (const float*)d_in[29];
  const float* clnb = (const float*)d_in[30];
  const float* chw  = (const float*)d_in[31];
  const float* chb  = (const float*)d_in[32];

  unsigned short* featb = (unsigned short*)d_ws;   // [2][NN*HD] bf16
  float* out = (float*)d_out;

  feat_kernel<<<256, 512, 0, stream>>>(
      x, aw1, ab1, aw2, ab2, aflnw, aflnb,
      cw1, cb1, cw2, cb2, cflnw, cflnb, featb);

  lstm_head_kernel<<<256, 512, 0, stream>>>(
      done, act,
      awih, awhh, a_b, alnw, alnb, ahw, ahb,
      cwih, cwhh, c_b, clnw, clnb, chw, chb,
      ah0, ac0, ch0, cc0,
      featb, out);
}